// Round 3
// baseline (3812.587 us; speedup 1.0000x reference)
//
#include <hip/hip_runtime.h>

#define N_B 256
#define T_SEQ 32

typedef short short8 __attribute__((ext_vector_type(8)));
typedef float floatx4 __attribute__((ext_vector_type(4)));
typedef unsigned short ushort_t;

// ---- scratch as device globals (no dependence on ws_size) ------------------
__device__ __align__(16) ushort_t g_Wxt[(size_t)4096 * 1024];      // 8 MB  Wx^T    [j][k]
__device__ __align__(16) ushort_t g_Wht[(size_t)4096 * 1024];      // 8 MB  Wh^T    [j][k]
__device__ __align__(16) ushort_t g_Wat[(size_t)4096 * 1024];      // 8 MB  Wattn^T [j][k]
__device__ __align__(16) ushort_t g_xb [(size_t)8192 * 1024];      // 16 MB bf16 x, row = t*256+n
__device__ __align__(16) float    g_px [(size_t)8192 * 4096];      // 134 MB fp32 x@Wx+b
__device__ __align__(16) ushort_t g_Ab [(size_t)N_B * 16384];      // 8 MB bf16 A [n][h][l]
__device__ __align__(16) ushort_t g_At [(size_t)N_B * 16384];      // 8 MB bf16 A [n][l][h]
__device__ __align__(16) ushort_t g_P  [(size_t)N_B * 4096 * 16];  // 32 MB bf16 P [n][j][l]
__device__ __align__(16) ushort_t g_Hc[2][N_B * 1024];             // h bf16 ping-pong
__device__ __align__(16) float    g_c [N_B * 1024];                // fp32 cell state (init only)
__device__ __align__(16) float    g_lg[3][N_B][16];                // rotated logit accumulators
__device__ unsigned int g_bar;                                     // grid barrier counter

__device__ __forceinline__ float bf2f(ushort_t u){
    union { unsigned int i; float f; } v; v.i = ((unsigned int)u) << 16; return v.f;
}
__device__ __forceinline__ ushort_t f2bf(float f){
    union { unsigned int i; float f; } v; v.f = f;
    unsigned int i = v.i;
    unsigned int r = (i + 0x7FFFu + ((i >> 16) & 1u)) >> 16;
    return (ushort_t)r;
}
__device__ __forceinline__ float fast_tanh(float x){
    float e = __expf(2.f * x);
    return 1.f - 2.f / (e + 1.f);
}
// async global->LDS, 16B per lane; lds dest = wave-uniform base + lane*16
__device__ __forceinline__ void gload16(const ushort_t* g, ushort_t* l) {
    __builtin_amdgcn_global_load_lds((const __attribute__((address_space(1))) void*)g,
                                     (__attribute__((address_space(3))) void*)l, 16, 0, 0);
}
__device__ __forceinline__ void unp8(uint4 u, float* f) {
    const ushort_t* s = (const ushort_t*)&u;
    #pragma unroll
    for (int i = 0; i < 8; ++i) f[i] = bf2f(s[i]);
}

// ---------------------------------------------------------------------------
// x (fp32 [n][t][d]) -> g_xb (bf16, row t*256+n). grid 8192 x 128.
// ---------------------------------------------------------------------------
__global__ __launch_bounds__(128) void cvt_x(const float* __restrict__ x)
{
    int b = blockIdx.x;                 // in-row = n*32 + t
    int n = b >> 5, tt = b & 31;
    int tid = threadIdx.x;
    const float* src = x + (size_t)b * 1024 + tid * 8;
    float4 a = *(const float4*)src;
    float4 c = *(const float4*)(src + 4);
    ushort_t r[8];
    r[0]=f2bf(a.x); r[1]=f2bf(a.y); r[2]=f2bf(a.z); r[3]=f2bf(a.w);
    r[4]=f2bf(c.x); r[5]=f2bf(c.y); r[6]=f2bf(c.z); r[7]=f2bf(c.w);
    *(uint4*)(g_xb + (size_t)(tt * 256 + n) * 1024 + tid * 8) = *(const uint4*)r;
}

// ---------------------------------------------------------------------------
// A fp32 [n][h][l] -> g_Ab bf16 (same layout) + g_At bf16 [n][l][h].
// grid 256 x 256.
// ---------------------------------------------------------------------------
__global__ __launch_bounds__(256) void cvt_a(const float* __restrict__ A)
{
    int n = blockIdx.x, tid = threadIdx.x;
    int h0 = tid * 4;
    const float* ap = A + (size_t)n * 16384;
    ushort_t tmp[4][16];
    #pragma unroll
    for (int i = 0; i < 4; ++i) {
        const float* row = ap + (size_t)(h0 + i) * 16;
        #pragma unroll
        for (int l = 0; l < 16; ++l) tmp[i][l] = f2bf(row[l]);
        ushort_t* dst = g_Ab + (size_t)n * 16384 + (size_t)(h0 + i) * 16;
        *(uint4*)dst       = *(const uint4*)&tmp[i][0];
        *(uint4*)(dst + 8) = *(const uint4*)&tmp[i][8];
    }
    #pragma unroll
    for (int l = 0; l < 16; ++l) {
        ushort_t pk[4] = { tmp[0][l], tmp[1][l], tmp[2][l], tmp[3][l] };
        *(uint2*)(g_At + (size_t)n * 16384 + (size_t)l * 1024 + h0) = *(const uint2*)pk;
    }
}

// ---------------------------------------------------------------------------
// Prepack W^T -> [j][k] bf16 (4096 x 1024). which: 0=Wx, 1=Wh, 2=Wattn.
// grid (16,64) x 256.
// ---------------------------------------------------------------------------
__global__ __launch_bounds__(256) void prepack_wT(const float* __restrict__ src, int which)
{
    __shared__ ushort_t tile[64][66];
    ushort_t* dst = (which == 0) ? g_Wxt : (which == 1) ? g_Wht : g_Wat;
    int k0 = blockIdx.x * 64, j0 = blockIdx.y * 64;
    int c = threadIdx.x & 63, r4 = threadIdx.x >> 6;
    for (int rr = 0; rr < 64; rr += 4) {
        int r = rr + r4;
        tile[r][c] = f2bf(src[(size_t)(k0 + r) * 4096 + j0 + c]);
    }
    __syncthreads();
    for (int rr = 0; rr < 64; rr += 4) {
        int j = rr + r4;
        dst[(size_t)(j0 + j) * 1024 + k0 + c] = tile[c][j];
    }
}

// ---------------------------------------------------------------------------
// Zero the rotated logit buffers + grid-barrier counter (per-replay reset).
// grid 48 x 256 (48*256 = 12288 = 3*256*16).
// ---------------------------------------------------------------------------
__global__ __launch_bounds__(256) void zero_lg()
{
    int i = blockIdx.x * 256 + threadIdx.x;
    if (i == 0) g_bar = 0u;
    ((float*)g_lg)[i] = 0.f;
}

// ---------------------------------------------------------------------------
// Init: h0 = c0 = mean over 16 spatial of A; accumulate t=0 logits into
// g_lg[0] (fp32 atomics, 4 chunk-blocks per n). grid 1024 x 256.
// ---------------------------------------------------------------------------
__global__ __launch_bounds__(256) void init_hc(const float* __restrict__ A)
{
    __shared__ float l1[16 * 257];     // [l][t] padded
    __shared__ float l2[16 * 16];      // [l][seg]
    int b = blockIdx.x;
    int n = b >> 2;
    int tid = threadIdx.x;
    int gid = b * 256 + tid;           // (n, h) with h = (b&3)*256+tid
    const float* ap = A + ((size_t)gid << 4);
    float a[16];
    *(float4*)(a)      = *(const float4*)(ap);
    *(float4*)(a + 4)  = *(const float4*)(ap + 4);
    *(float4*)(a + 8)  = *(const float4*)(ap + 8);
    *(float4*)(a + 12) = *(const float4*)(ap + 12);
    float s = 0.f;
    #pragma unroll
    for (int l = 0; l < 16; ++l) s += a[l];
    s *= (1.0f / 16.0f);
    g_Hc[0][gid] = f2bf(s);
    g_c[gid] = s;
    // partial logits over this 256-h chunk: p[l] = sum_h h0[h]*A[n][h][l]
    #pragma unroll
    for (int l = 0; l < 16; ++l) l1[l * 257 + tid] = s * a[l];
    __syncthreads();
    {
        int l = tid >> 4, seg = tid & 15;
        float s2 = 0.f;
        #pragma unroll
        for (int i = 0; i < 16; ++i) s2 += l1[l * 257 + seg * 16 + i];
        l2[l * 16 + seg] = s2;
    }
    __syncthreads();
    if (tid < 16) {
        float lg = 0.f;
        #pragma unroll
        for (int i = 0; i < 16; ++i) lg += l2[tid * 16 + i];
        atomicAdd(&g_lg[0][n][tid], lg);
    }
}

// ---------------------------------------------------------------------------
// Hoisted GEMM 1: g_px[t*256+n][j] = x@Wx + b. M=8192, N=4096, K=1024.
// ---------------------------------------------------------------------------
__global__ __launch_bounds__(256) void xw_gemm(const float* __restrict__ bias)
{
    __shared__ __align__(16) char smem[33280];
    ushort_t* lA = (ushort_t*)smem;                 // 128 x 64 bf16 (16 KB)
    ushort_t* lB = (ushort_t*)(smem + 16384);       // 128 x 64 bf16 (16 KB)
    float*    lP = (float*)smem;                    // 64 x 130 fp32 (epilogue alias)

    int b = blockIdx.x;
    int xcd = b & 7, q = b >> 3;                    // bijective: 2048 % 8 == 0
    int mb = xcd * 8 + (q & 7), jb = q >> 3;        // mb 0..63, jb 0..31
    int m0 = mb * 128, j0 = jb * 128;
    int tid = threadIdx.x, lane = tid & 63, wv = tid >> 6;
    int wm = wv >> 1, wn = wv & 1;
    int lm = lane & 15, quad = lane >> 4;

    int srow = lane >> 3, sseg = lane & 7;
    const ushort_t* gA = g_xb  + (size_t)(m0 + wv * 32 + srow) * 1024 + (sseg ^ srow) * 8;
    const ushort_t* gB = g_Wxt + (size_t)(j0 + wv * 32 + srow) * 1024 + (sseg ^ srow) * 8;

    floatx4 acc[4][4] = {};
    for (int kt = 0; kt < 16; ++kt) {
        __syncthreads();
        #pragma unroll
        for (int i = 0; i < 4; ++i) {
            gload16(gA + (size_t)i * 8 * 1024 + kt * 64, lA + (wv * 32 + i * 8) * 64);
            gload16(gB + (size_t)i * 8 * 1024 + kt * 64, lB + (wv * 32 + i * 8) * 64);
        }
        __syncthreads();
        #pragma unroll
        for (int ks = 0; ks < 2; ++ks) {
            short8 af[4], bf[4];
            #pragma unroll
            for (int i = 0; i < 4; ++i) {
                int row = wm*64 + i*16 + lm;
                af[i] = *(const short8*)(lA + row * 64 + (((ks*4 + quad) ^ (row & 7)) * 8));
            }
            #pragma unroll
            for (int j = 0; j < 4; ++j) {
                int row = wn*64 + j*16 + lm;
                bf[j] = *(const short8*)(lB + row * 64 + (((ks*4 + quad) ^ (row & 7)) * 8));
            }
            #pragma unroll
            for (int i = 0; i < 4; ++i)
                #pragma unroll
                for (int j = 0; j < 4; ++j)
                    acc[i][j] = __builtin_amdgcn_mfma_f32_16x16x32_bf16(af[i], bf[j], acc[i][j], 0, 0, 0);
        }
    }

    #pragma unroll
    for (int ph = 0; ph < 2; ++ph) {
        __syncthreads();
        if (wm == ph) {
            #pragma unroll
            for (int i = 0; i < 4; ++i)
                #pragma unroll
                for (int j = 0; j < 4; ++j)
                    #pragma unroll
                    for (int qq = 0; qq < 4; ++qq)
                        lP[(i*16 + quad*4 + qq) * 130 + wn*64 + j*16 + lm] = acc[i][j][qq];
        }
        __syncthreads();
        int row = tid >> 2, seg = tid & 3;
        const float* src = lP + row * 130 + seg * 32;
        float* dst = g_px + (size_t)(m0 + ph * 64 + row) * 4096 + j0 + seg * 32;
        const float* bb = bias + j0 + seg * 32;
        #pragma unroll
        for (int i = 0; i < 8; ++i) {
            float4 v = *(const float4*)(src + i * 4);
            float4 w = *(const float4*)(bb + i * 4);
            v.x += w.x; v.y += w.y; v.z += w.z; v.w += w.w;
            *(float4*)(dst + i * 4) = v;
        }
    }
}

// ---------------------------------------------------------------------------
// Hoisted GEMM 2: P[n][j][l] = At @ Wattn^T. grid 1024 x 256.
// ---------------------------------------------------------------------------
__global__ __launch_bounds__(256) void pw_gemm()
{
    __shared__ __align__(16) char smem[32768];
    ushort_t* lA = (ushort_t*)smem;
    ushort_t* lB = (ushort_t*)(smem + 16384);

    int b = blockIdx.x;
    int xcd = b & 7, q = b >> 3;
    int mb = xcd * 4 + (q & 3), jb = q >> 2;
    int m0 = mb * 128, j0 = jb * 128;
    int tid = threadIdx.x, lane = tid & 63, wv = tid >> 6;
    int wm = wv >> 1, wn = wv & 1;
    int lm = lane & 15, quad = lane >> 4;

    int srow = lane >> 3, sseg = lane & 7;
    const ushort_t* gA = g_At  + (size_t)(m0 + wv * 32 + srow) * 1024 + (sseg ^ srow) * 8;
    const ushort_t* gB = g_Wat + (size_t)(j0 + wv * 32 + srow) * 1024 + (sseg ^ srow) * 8;

    floatx4 acc[4][4] = {};
    for (int kt = 0; kt < 16; ++kt) {
        __syncthreads();
        #pragma unroll
        for (int i = 0; i < 4; ++i) {
            gload16(gA + (size_t)i * 8 * 1024 + kt * 64, lA + (wv * 32 + i * 8) * 64);
            gload16(gB + (size_t)i * 8 * 1024 + kt * 64, lB + (wv * 32 + i * 8) * 64);
        }
        __syncthreads();
        #pragma unroll
        for (int ks = 0; ks < 2; ++ks) {
            short8 af[4], bf[4];
            #pragma unroll
            for (int i = 0; i < 4; ++i) {
                int row = wm*64 + i*16 + lm;
                af[i] = *(const short8*)(lA + row * 64 + (((ks*4 + quad) ^ (row & 7)) * 8));
            }
            #pragma unroll
            for (int j = 0; j < 4; ++j) {
                int row = wn*64 + j*16 + lm;
                bf[j] = *(const short8*)(lB + row * 64 + (((ks*4 + quad) ^ (row & 7)) * 8));
            }
            #pragma unroll
            for (int i = 0; i < 4; ++i)
                #pragma unroll
                for (int j = 0; j < 4; ++j)
                    acc[i][j] = __builtin_amdgcn_mfma_f32_16x16x32_bf16(af[i], bf[j], acc[i][j], 0, 0, 0);
        }
    }

    int n8 = mb * 8;
    #pragma unroll
    for (int i = 0; i < 4; ++i) {
        #pragma unroll
        for (int jf = 0; jf < 4; ++jf) {
            ushort_t pk[4];
            #pragma unroll
            for (int q4 = 0; q4 < 4; ++q4) pk[q4] = f2bf(acc[i][jf][q4]);
            size_t off = ((size_t)(n8 + wm * 4 + i) * 4096
                          + (j0 + wn * 64 + jf * 16 + lm)) * 16 + quad * 4;
            *(uint2*)(g_P + off) = *(const uint2*)pk;
        }
    }
}

// ---------------------------------------------------------------------------
// Persistent step loop: one kernel runs all T_SEQ steps with a device-scope
// grid barrier between steps. 512 blocks x 256 thr, 2 blocks/CU co-resident
// (launch_bounds(256,2), LDS 51.2 KB <= 80 KB/block budget). Per step:
// softmax from g_lg (3-phase rotated fp32 accumulators; read@t, zero@t for
// t+1's accumulation, atomicAdd@t for t+1 -> every hazard pair separated by
// a grid barrier), h@Wh GEMM (dbuf, counted vmcnt), fused LSTM epilogue with
// register-resident cell state, w.P attention add, out/H writes, logit
// atomics. Barrier: monotonic counter, thread-0 arrive+spin, threadfence
// release/acquire (agent scope -> cross-XCD L2 wb/inv).
// ---------------------------------------------------------------------------
__global__ __launch_bounds__(256, 2) void step_loop(float* __restrict__ out)
{
    __shared__ __align__(16) char smem[51200];
    ushort_t* lA0 = (ushort_t*)smem;                 // 32x128 bf16 (8 KB)
    ushort_t* lA1 = (ushort_t*)(smem + 8192);
    ushort_t* lB0 = (ushort_t*)(smem + 16384);       // 64x128 bf16 (16 KB)
    ushort_t* lB1 = (ushort_t*)(smem + 32768);
    float*    lP  = (float*)smem;                    // [4][32*68] epilogue alias
    float*    lq  = (float*)smem;                    // [512*17] logit alias
    float*    lw  = (float*)(smem + 49152);          // [32][16] softmax weights

    int b = blockIdx.x;
    int xcd = b & 7, r = b >> 3;
    int jt = xcd * 8 + (r & 7), nt = r >> 3;
    int n0 = nt * 32, hh0 = jt * 16;
    int tid = threadIdx.x, lane = tid & 63, wv = tid >> 6;
    int lm = lane & 15, quad = lane >> 4;
    int srow = lane >> 4, sseg = lane & 15;

    const ushort_t* gB0 = g_Wht + (size_t)(wv * 1024 + hh0 + srow) * 1024;

    // persistent block-private cell state: 2 elements per thread
    float creg[2];
    {
        int nlA = tid >> 4, hlA = tid & 15;
        creg[0] = g_c[(n0 + nlA) * 1024 + hh0 + hlA];
        creg[1] = g_c[(n0 + 16 + nlA) * 1024 + hh0 + hlA];
    }

    for (int t = 0; t < T_SEQ; ++t) {
        if (t) {
            __syncthreads();
            if (tid == 0) {
                __threadfence();                             // release our writes
                atomicAdd(&g_bar, 1u);
                while (__hip_atomic_load(&g_bar, __ATOMIC_ACQUIRE,
                                         __HIP_MEMORY_SCOPE_AGENT) < 512u * (unsigned)t)
                    __builtin_amdgcn_s_sleep(2);
            }
            __syncthreads();
            __threadfence();                                 // acquire for all threads
        }

        const ushort_t* Hin  = g_Hc[t & 1];
        ushort_t*       Hout = g_Hc[(t + 1) & 1];
        const ushort_t* gA0  = Hin + (size_t)(n0 + wv * 8 + srow) * 1024;

        // ---- prologue: issue tile-0 staging first (latency hides under softmax)
        #pragma unroll
        for (int i = 0; i < 2; ++i) {
            int rlow = (wv * 8 + i * 4 + srow) & 15;
            gload16(gA0 + (size_t)i * 4 * 1024 + (sseg ^ rlow) * 8, lA0 + (wv * 8 + i * 4) * 128);
        }
        #pragma unroll
        for (int i = 0; i < 4; ++i) {
            int rlow = i * 4 + srow;
            gload16(gB0 + (size_t)i * 4 * 1024 + (sseg ^ rlow) * 8, lB0 + (wv * 16 + i * 4) * 128);
        }

        // ---- softmax weights for this block's 32 n (redundant across jt) ----
        #pragma unroll
        for (int e = 0; e < 2; ++e) {
            int idx = tid + e * 256;
            int nl = idx >> 4, l = idx & 15;
            float v = g_lg[t % 3][n0 + nl][l] * 0.03125f;    // 1/sqrt(H)
            float mx = v;
            mx = fmaxf(mx, __shfl_xor(mx, 1));
            mx = fmaxf(mx, __shfl_xor(mx, 2));
            mx = fmaxf(mx, __shfl_xor(mx, 4));
            mx = fmaxf(mx, __shfl_xor(mx, 8));
            float ex = __expf(v - mx);
            float sm = ex;
            sm += __shfl_xor(sm, 1);
            sm += __shfl_xor(sm, 2);
            sm += __shfl_xor(sm, 4);
            sm += __shfl_xor(sm, 8);
            lw[nl * 16 + l] = ex / sm;
        }
        // zero the buffer that window t+1 will accumulate into (rotation-safe)
        if (tid < 8) ((float*)g_lg[(t + 2) % 3])[b * 8 + tid] = 0.f;

        // ---- K-loop: 8 double-buffered iters, counted vmcnt ----
        floatx4 acc[2][4] = {};
        int segk = wv * 4 + quad;
        for (int it = 0; it < 8; ++it) {
            ushort_t* cA = (it & 1) ? lA1 : lA0;
            ushort_t* cB = (it & 1) ? lB1 : lB0;
            ushort_t* nA = (it & 1) ? lA0 : lA1;
            ushort_t* nB = (it & 1) ? lB0 : lB1;
            if (it < 7) {
                int kk = (it + 1) * 128;
                #pragma unroll
                for (int i = 0; i < 2; ++i) {
                    int rlow = (wv * 8 + i * 4 + srow) & 15;
                    gload16(gA0 + (size_t)i * 4 * 1024 + kk + (sseg ^ rlow) * 8,
                            nA + (wv * 8 + i * 4) * 128);
                }
                #pragma unroll
                for (int i = 0; i < 4; ++i) {
                    int rlow = i * 4 + srow;
                    gload16(gB0 + (size_t)i * 4 * 1024 + kk + (sseg ^ rlow) * 8,
                            nB + (wv * 16 + i * 4) * 128);
                }
                asm volatile("s_waitcnt vmcnt(6)" ::: "memory");
            } else {
                asm volatile("s_waitcnt vmcnt(0)" ::: "memory");
            }
            __builtin_amdgcn_s_barrier();
            short8 af[2], bq[4];
            #pragma unroll
            for (int i = 0; i < 2; ++i)
                af[i] = *(const short8*)(cA + (i * 16 + lm) * 128 + ((segk ^ lm) * 8));
            #pragma unroll
            for (int j = 0; j < 4; ++j)
                bq[j] = *(const short8*)(cB + (j * 16 + lm) * 128 + ((segk ^ lm) * 8));
            #pragma unroll
            for (int i = 0; i < 2; ++i)
                #pragma unroll
                for (int j = 0; j < 4; ++j)
                    acc[i][j] = __builtin_amdgcn_mfma_f32_16x16x32_bf16(af[i], bq[j], acc[i][j], 0, 0, 0);
            asm volatile("s_waitcnt lgkmcnt(0)" ::: "memory");
            __builtin_amdgcn_s_barrier();
        }

        // ---- wave-private partial store ----
        float* my = lP + wv * (32 * 68);
        #pragma unroll
        for (int i = 0; i < 2; ++i)
            #pragma unroll
            for (int j = 0; j < 4; ++j)
                #pragma unroll
                for (int q = 0; q < 4; ++q)
                    my[(i * 16 + quad * 4 + q) * 68 + j * 16 + lm] = acc[i][j][q];
        __syncthreads();

        // ---- LSTM pointwise: 4 wave-partials + px + sum_l w[l]*P[n][j][l] ----
        float hsave[2];
        #pragma unroll
        for (int e = 0; e < 2; ++e) {
            int idx = tid + e * 256;           // (nl, hl)
            int nl = idx >> 4, hl = idx & 15;
            int base = nl * 68 + hl;
            float s0 = lP[base]      + lP[2176 + base]      + lP[4352 + base]      + lP[6528 + base];
            float s1 = lP[base + 16] + lP[2176 + base + 16] + lP[4352 + base + 16] + lP[6528 + base + 16];
            float s2 = lP[base + 32] + lP[2176 + base + 32] + lP[4352 + base + 32] + lP[6528 + base + 32];
            float s3 = lP[base + 48] + lP[2176 + base + 48] + lP[4352 + base + 48] + lP[6528 + base + 48];
            float wreg[16];
            #pragma unroll
            for (int k = 0; k < 4; ++k)
                *(float4*)(wreg + k * 4) = *(const float4*)(lw + nl * 16 + k * 4);
            const ushort_t* pb = g_P + ((size_t)(n0 + nl) * 4096 + hh0 + hl) * 16;
            float at[4];
            #pragma unroll
            for (int g = 0; g < 4; ++g) {
                const ushort_t* pg = pb + (size_t)g * 1024 * 16;
                float pv[16];
                unp8(*(const uint4*)pg, pv);
                unp8(*(const uint4*)(pg + 8), pv + 8);
                float a = 0.f;
                #pragma unroll
                for (int l = 0; l < 16; ++l) a += wreg[l] * pv[l];
                at[g] = a;
            }
            const float* px = g_px + ((size_t)t * 256 + (n0 + nl)) * 4096 + hh0 + hl;
            float ai  = s0 + px[0]    + at[0];
            float afv = s1 + px[1024] + at[1];
            float ao  = s2 + px[2048] + at[2];
            float ag  = s3 + px[3072] + at[3];
            float iv = 1.f / (1.f + __expf(-ai));
            float fv = 1.f / (1.f + __expf(-afv));
            float ov = 1.f / (1.f + __expf(-ao));
            float gv = fast_tanh(ag);
            float cnew = fv * creg[e] + iv * gv;
            float hnew = ov * fast_tanh(cnew);
            creg[e] = cnew;
            int ng = n0 + nl, hg = hh0 + hl;
            Hout[ng * 1024 + hg] = f2bf(hnew);
            out[(size_t)ng * (T_SEQ * 1024) + (size_t)t * 1024 + hg] = hnew;
            hsave[e] = hnew;
        }

        // ---- logit partial for step t+1 (atomicAdd into rotated buffer) ----
        if (t < T_SEQ - 1) {
            __syncthreads();               // lP reads done before lq overwrite
            #pragma unroll
            for (int e = 0; e < 2; ++e) {
                int idx = tid + e * 256;
                int nl = idx >> 4, hl = idx & 15;
                const ushort_t* ar = g_Ab + (size_t)(n0 + nl) * 16384 + (size_t)(hh0 + hl) * 16;
                float av[16];
                unp8(*(const uint4*)ar, av);
                unp8(*(const uint4*)(ar + 8), av + 8);
                float hv = hsave[e];
                #pragma unroll
                for (int l = 0; l < 16; ++l)
                    lq[(nl * 16 + l) * 17 + hl] = hv * av[l];
            }
            __syncthreads();
            #pragma unroll
            for (int e = 0; e < 2; ++e) {
                int idx = tid + e * 256;
                int nl = idx >> 4, l = idx & 15;
                float s = 0.f;
                #pragma unroll
                for (int k = 0; k < 16; ++k) s += lq[(nl * 16 + l) * 17 + k];
                atomicAdd(&g_lg[(t + 1) % 3][n0 + nl][l], s);
            }
        }
    }
}

// ---------------------------------------------------------------------------
extern "C" void kernel_launch(void* const* d_in, const int* in_sizes, int n_in,
                              void* d_out, int out_size, void* d_ws, size_t ws_size,
                              hipStream_t stream) {
    const float* x     = (const float*)d_in[0];
    const float* A     = (const float*)d_in[1];
    const float* Wx    = (const float*)d_in[2];
    const float* Wh    = (const float*)d_in[3];
    const float* Wattn = (const float*)d_in[4];
    const float* bias  = (const float*)d_in[5];
    float* out = (float*)d_out;

    cvt_x<<<8192, 128, 0, stream>>>(x);
    cvt_a<<<256, 256, 0, stream>>>(A);
    prepack_wT<<<dim3(16, 64), 256, 0, stream>>>(Wx, 0);
    prepack_wT<<<dim3(16, 64), 256, 0, stream>>>(Wh, 1);
    prepack_wT<<<dim3(16, 64), 256, 0, stream>>>(Wattn, 2);
    zero_lg<<<48, 256, 0, stream>>>();
    init_hc<<<1024, 256, 0, stream>>>(A);
    xw_gemm<<<2048, 256, 0, stream>>>(bias);
    pw_gemm<<<1024, 256, 0, stream>>>();
    step_loop<<<512, 256, 0, stream>>>(out);
}

// Round 4
// 876.841 us; speedup vs baseline: 4.3481x; 4.3481x over previous
//
#include <hip/hip_runtime.h>

#define N_B 256
#define T_SEQ 32

typedef short short8 __attribute__((ext_vector_type(8)));
typedef float floatx4 __attribute__((ext_vector_type(4)));
typedef unsigned short ushort_t;

// ---- scratch as device globals (no dependence on ws_size) ------------------
__device__ __align__(16) ushort_t g_W2 [(size_t)4096 * 2048];      // 16 MB [j][k]=[Wh^T|Wx^T]
__device__ __align__(16) ushort_t g_Wat[(size_t)4096 * 1024];      // 8 MB  Wattn^T [j][k]
__device__ __align__(16) ushort_t g_xb [(size_t)8192 * 1024];      // 16 MB bf16 x, row = t*256+n
__device__ __align__(16) ushort_t g_Ab [(size_t)N_B * 16384];      // 8 MB bf16 A [n][h][l]
__device__ __align__(16) ushort_t g_At [(size_t)N_B * 16384];      // 8 MB bf16 A [n][l][h]
__device__ __align__(16) ushort_t g_P  [(size_t)N_B * 4096 * 16];  // 32 MB bf16 P [n][j][l]
__device__ __align__(16) ushort_t g_Hc[2][N_B * 1024];             // h bf16 ping-pong
__device__ __align__(16) float    g_c [N_B * 1024];                // fp32 cell state
__device__ __align__(16) float    g_lg[3][N_B][16];                // rotated logit accumulators

__device__ __forceinline__ float bf2f(ushort_t u){
    union { unsigned int i; float f; } v; v.i = ((unsigned int)u) << 16; return v.f;
}
__device__ __forceinline__ ushort_t f2bf(float f){
    union { unsigned int i; float f; } v; v.f = f;
    unsigned int i = v.i;
    unsigned int r = (i + 0x7FFFu + ((i >> 16) & 1u)) >> 16;
    return (ushort_t)r;
}
__device__ __forceinline__ float fast_tanh(float x){
    float e = __expf(2.f * x);
    return 1.f - 2.f / (e + 1.f);
}
// async global->LDS, 16B per lane; lds dest = wave-uniform base + lane*16
__device__ __forceinline__ void gload16(const ushort_t* g, ushort_t* l) {
    __builtin_amdgcn_global_load_lds((const __attribute__((address_space(1))) void*)g,
                                     (__attribute__((address_space(3))) void*)l, 16, 0, 0);
}
__device__ __forceinline__ void unp8(uint4 u, float* f) {
    const ushort_t* s = (const ushort_t*)&u;
    #pragma unroll
    for (int i = 0; i < 8; ++i) f[i] = bf2f(s[i]);
}

// ---------------------------------------------------------------------------
// x (fp32 [n][t][d]) -> g_xb (bf16, row t*256+n). grid 8192 x 128.
// ---------------------------------------------------------------------------
__global__ __launch_bounds__(128) void cvt_x(const float* __restrict__ x)
{
    int b = blockIdx.x;                 // in-row = n*32 + t
    int n = b >> 5, tt = b & 31;
    int tid = threadIdx.x;
    const float* src = x + (size_t)b * 1024 + tid * 8;
    float4 a = *(const float4*)src;
    float4 c = *(const float4*)(src + 4);
    ushort_t r[8];
    r[0]=f2bf(a.x); r[1]=f2bf(a.y); r[2]=f2bf(a.z); r[3]=f2bf(a.w);
    r[4]=f2bf(c.x); r[5]=f2bf(c.y); r[6]=f2bf(c.z); r[7]=f2bf(c.w);
    *(uint4*)(g_xb + (size_t)(tt * 256 + n) * 1024 + tid * 8) = *(const uint4*)r;
}

// ---------------------------------------------------------------------------
// A fp32 [n][h][l] -> g_Ab bf16 (same layout) + g_At bf16 [n][l][h].
// grid 256 x 256.
// ---------------------------------------------------------------------------
__global__ __launch_bounds__(256) void cvt_a(const float* __restrict__ A)
{
    int n = blockIdx.x, tid = threadIdx.x;
    int h0 = tid * 4;
    const float* ap = A + (size_t)n * 16384;
    ushort_t tmp[4][16];
    #pragma unroll
    for (int i = 0; i < 4; ++i) {
        const float* row = ap + (size_t)(h0 + i) * 16;
        #pragma unroll
        for (int l = 0; l < 16; ++l) tmp[i][l] = f2bf(row[l]);
        ushort_t* dst = g_Ab + (size_t)n * 16384 + (size_t)(h0 + i) * 16;
        *(uint4*)dst       = *(const uint4*)&tmp[i][0];
        *(uint4*)(dst + 8) = *(const uint4*)&tmp[i][8];
    }
    #pragma unroll
    for (int l = 0; l < 16; ++l) {
        ushort_t pk[4] = { tmp[0][l], tmp[1][l], tmp[2][l], tmp[3][l] };
        *(uint2*)(g_At + (size_t)n * 16384 + (size_t)l * 1024 + h0) = *(const uint2*)pk;
    }
}

// ---------------------------------------------------------------------------
// Prepack [Wh^T | Wx^T] -> g_W2 [j][k2] (4096 x 2048). grid (32,64) x 256.
// ---------------------------------------------------------------------------
__global__ __launch_bounds__(256) void prepack_w2(
    const float* __restrict__ Wh, const float* __restrict__ Wx)
{
    __shared__ ushort_t tile[64][66];
    int k0 = blockIdx.x * 64, j0 = blockIdx.y * 64;
    const float* src = (k0 < 1024) ? Wh : Wx;
    int krel = (k0 < 1024) ? k0 : k0 - 1024;
    int c = threadIdx.x & 63, r4 = threadIdx.x >> 6;
    for (int rr = 0; rr < 64; rr += 4) {
        int r = rr + r4;
        tile[r][c] = f2bf(src[(size_t)(krel + r) * 4096 + j0 + c]);
    }
    __syncthreads();
    for (int rr = 0; rr < 64; rr += 4) {
        int j = rr + r4;
        g_W2[(size_t)(j0 + j) * 2048 + k0 + c] = tile[c][j];
    }
}

// ---------------------------------------------------------------------------
// Prepack Wattn^T -> g_Wat [j][k] (4096 x 1024). grid (16,64) x 256.
// ---------------------------------------------------------------------------
__global__ __launch_bounds__(256) void prepack_wat(const float* __restrict__ Wattn)
{
    __shared__ ushort_t tile[64][66];
    int k0 = blockIdx.x * 64, j0 = blockIdx.y * 64;
    int c = threadIdx.x & 63, r4 = threadIdx.x >> 6;
    for (int rr = 0; rr < 64; rr += 4) {
        int r = rr + r4;
        tile[r][c] = f2bf(Wattn[(size_t)(k0 + r) * 4096 + j0 + c]);
    }
    __syncthreads();
    for (int rr = 0; rr < 64; rr += 4) {
        int j = rr + r4;
        g_Wat[(size_t)(j0 + j) * 1024 + k0 + c] = tile[c][j];
    }
}

// ---------------------------------------------------------------------------
// Zero the rotated logit buffers (per-replay reset). grid 48 x 256.
// ---------------------------------------------------------------------------
__global__ __launch_bounds__(256) void zero_lg()
{
    int i = blockIdx.x * 256 + threadIdx.x;
    ((float*)g_lg)[i] = 0.f;
}

// ---------------------------------------------------------------------------
// Init: h0 = c0 = mean over 16 spatial of A; accumulate t=0 logits into
// g_lg[0] (fp32 atomics, 4 chunk-blocks per n). grid 1024 x 256.
// ---------------------------------------------------------------------------
__global__ __launch_bounds__(256) void init_hc(const float* __restrict__ A)
{
    __shared__ float l1[16 * 257];     // [l][t] padded
    __shared__ float l2[16 * 16];      // [l][seg]
    int b = blockIdx.x;
    int n = b >> 2;
    int tid = threadIdx.x;
    int gid = b * 256 + tid;           // (n, h) with h = (b&3)*256+tid
    const float* ap = A + ((size_t)gid << 4);
    float a[16];
    *(float4*)(a)      = *(const float4*)(ap);
    *(float4*)(a + 4)  = *(const float4*)(ap + 4);
    *(float4*)(a + 8)  = *(const float4*)(ap + 8);
    *(float4*)(a + 12) = *(const float4*)(ap + 12);
    float s = 0.f;
    #pragma unroll
    for (int l = 0; l < 16; ++l) s += a[l];
    s *= (1.0f / 16.0f);
    g_Hc[0][gid] = f2bf(s);
    g_c[gid] = s;
    // partial logits over this 256-h chunk: p[l] = sum_h h0[h]*A[n][h][l]
    #pragma unroll
    for (int l = 0; l < 16; ++l) l1[l * 257 + tid] = s * a[l];
    __syncthreads();
    {
        int l = tid >> 4, seg = tid & 15;
        float s2 = 0.f;
        #pragma unroll
        for (int i = 0; i < 16; ++i) s2 += l1[l * 257 + seg * 16 + i];
        l2[l * 16 + seg] = s2;
    }
    __syncthreads();
    if (tid < 16) {
        float lg = 0.f;
        #pragma unroll
        for (int i = 0; i < 16; ++i) lg += l2[tid * 16 + i];
        atomicAdd(&g_lg[0][n][tid], lg);
    }
}

// ---------------------------------------------------------------------------
// Hoisted GEMM: P[n][j][l] = At @ Wattn^T. M=4096 ((n,l)), N=4096, K=1024.
// grid 1024 x 256.
// ---------------------------------------------------------------------------
__global__ __launch_bounds__(256) void pw_gemm()
{
    __shared__ __align__(16) char smem[32768];
    ushort_t* lA = (ushort_t*)smem;
    ushort_t* lB = (ushort_t*)(smem + 16384);

    int b = blockIdx.x;
    int xcd = b & 7, q = b >> 3;
    int mb = xcd * 4 + (q & 3), jb = q >> 2;
    int m0 = mb * 128, j0 = jb * 128;
    int tid = threadIdx.x, lane = tid & 63, wv = tid >> 6;
    int wm = wv >> 1, wn = wv & 1;
    int lm = lane & 15, quad = lane >> 4;

    int srow = lane >> 3, sseg = lane & 7;
    const ushort_t* gA = g_At  + (size_t)(m0 + wv * 32 + srow) * 1024 + (sseg ^ srow) * 8;
    const ushort_t* gB = g_Wat + (size_t)(j0 + wv * 32 + srow) * 1024 + (sseg ^ srow) * 8;

    floatx4 acc[4][4] = {};
    for (int kt = 0; kt < 16; ++kt) {
        __syncthreads();
        #pragma unroll
        for (int i = 0; i < 4; ++i) {
            gload16(gA + (size_t)i * 8 * 1024 + kt * 64, lA + (wv * 32 + i * 8) * 64);
            gload16(gB + (size_t)i * 8 * 1024 + kt * 64, lB + (wv * 32 + i * 8) * 64);
        }
        __syncthreads();
        #pragma unroll
        for (int ks = 0; ks < 2; ++ks) {
            short8 af[4], bf[4];
            #pragma unroll
            for (int i = 0; i < 4; ++i) {
                int row = wm*64 + i*16 + lm;
                af[i] = *(const short8*)(lA + row * 64 + (((ks*4 + quad) ^ (row & 7)) * 8));
            }
            #pragma unroll
            for (int j = 0; j < 4; ++j) {
                int row = wn*64 + j*16 + lm;
                bf[j] = *(const short8*)(lB + row * 64 + (((ks*4 + quad) ^ (row & 7)) * 8));
            }
            #pragma unroll
            for (int i = 0; i < 4; ++i)
                #pragma unroll
                for (int j = 0; j < 4; ++j)
                    acc[i][j] = __builtin_amdgcn_mfma_f32_16x16x32_bf16(af[i], bf[j], acc[i][j], 0, 0, 0);
        }
    }

    int n8 = mb * 8;
    #pragma unroll
    for (int i = 0; i < 4; ++i) {
        #pragma unroll
        for (int jf = 0; jf < 4; ++jf) {
            ushort_t pk[4];
            #pragma unroll
            for (int q4 = 0; q4 < 4; ++q4) pk[q4] = f2bf(acc[i][jf][q4]);
            size_t off = ((size_t)(n8 + wm * 4 + i) * 4096
                          + (j0 + wn * 64 + jf * 16 + lm)) * 16 + quad * 4;
            *(uint2*)(g_P + off) = *(const uint2*)pk;
        }
    }
}

// ---------------------------------------------------------------------------
// Per-step GEMM v6: C[256x4096] = [h|x_t] @ [Wh;Wx] (K=2048) + bias + w.P
// + LSTM, ONE launch per step. In-kernel softmax from g_lg rotation:
// read buf[t%3], atomicAdd t+1 partials into buf[(t+1)%3], zero buf[(t+2)%3]
// -- every hazard pair separated by a launch boundary. 16 double-buffered
// K-iters (A source switches Hin->g_xb at k=1024), counted vmcnt(6), raw
// barriers. Grid 512 = 8 n-tiles x 64 j-strips, XCD-pinned, 2 blocks/CU.
// ---------------------------------------------------------------------------
__global__ __launch_bounds__(256, 2) void step_gemm(float* __restrict__ out,
                                                    const float* __restrict__ bias, int t)
{
    __shared__ __align__(16) char smem[51200];
    ushort_t* lA0 = (ushort_t*)smem;                 // 32x128 bf16 (8 KB)
    ushort_t* lA1 = (ushort_t*)(smem + 8192);
    ushort_t* lB0 = (ushort_t*)(smem + 16384);       // 64x128 bf16 (16 KB)
    ushort_t* lB1 = (ushort_t*)(smem + 32768);
    float*    lP  = (float*)smem;                    // [4][32*68] epilogue alias
    float*    lq  = (float*)smem;                    // [512*17] logit alias
    float*    lw  = (float*)(smem + 49152);          // [32][16] softmax weights

    const ushort_t* Hin  = g_Hc[t & 1];
    ushort_t*       Hout = g_Hc[(t + 1) & 1];

    int b = blockIdx.x;
    int xcd = b & 7, r = b >> 3;
    int jt = xcd * 8 + (r & 7), nt = r >> 3;
    int n0 = nt * 32, hh0 = jt * 16;
    int tid = threadIdx.x, lane = tid & 63, wv = tid >> 6;
    int lm = lane & 15, quad = lane >> 4;
    int srow = lane >> 4, sseg = lane & 15;

    // staging bases: A row n0+wv*8+srow; h-half (k<1024) vs x-half (k>=1024)
    const ushort_t* hbase = Hin  + (size_t)(n0 + wv * 8 + srow) * 1024;
    const ushort_t* xbase = g_xb + ((size_t)t * 256 + n0 + wv * 8 + srow) * 1024;
    const ushort_t* gB0   = g_W2 + (size_t)(wv * 1024 + hh0 + srow) * 2048;

    // ---- prologue: issue tile-0 staging (k=0, h source) ----
    #pragma unroll
    for (int i = 0; i < 2; ++i) {
        int rlow = (wv * 8 + i * 4 + srow) & 15;
        gload16(hbase + (size_t)i * 4 * 1024 + (sseg ^ rlow) * 8, lA0 + (wv * 8 + i * 4) * 128);
    }
    #pragma unroll
    for (int i = 0; i < 4; ++i) {
        int rlow = i * 4 + srow;
        gload16(gB0 + (size_t)i * 4 * 2048 + (sseg ^ rlow) * 8, lB0 + (wv * 16 + i * 4) * 128);
    }

    // ---- softmax weights for this block's 32 n (redundant across jt) ----
    #pragma unroll
    for (int e = 0; e < 2; ++e) {
        int idx = tid + e * 256;
        int nl = idx >> 4, l = idx & 15;
        float v = g_lg[t % 3][n0 + nl][l] * 0.03125f;    // 1/sqrt(H)
        float mx = v;
        mx = fmaxf(mx, __shfl_xor(mx, 1));
        mx = fmaxf(mx, __shfl_xor(mx, 2));
        mx = fmaxf(mx, __shfl_xor(mx, 4));
        mx = fmaxf(mx, __shfl_xor(mx, 8));
        float ex = __expf(v - mx);
        float sm = ex;
        sm += __shfl_xor(sm, 1);
        sm += __shfl_xor(sm, 2);
        sm += __shfl_xor(sm, 4);
        sm += __shfl_xor(sm, 8);
        lw[nl * 16 + l] = ex / sm;
    }
    // zero the buffer that step t+2 will read (accumulated at t+1); disjoint
    // 8-float slices over 512 blocks cover all 4096 floats exactly once.
    if (tid < 8) ((float*)g_lg[(t + 2) % 3])[b * 8 + tid] = 0.f;

    // ---- K-loop: 16 double-buffered iters, counted vmcnt ----
    floatx4 acc[2][4] = {};
    int segk = wv * 4 + quad;
    for (int it = 0; it < 16; ++it) {
        ushort_t* cA = (it & 1) ? lA1 : lA0;
        ushort_t* cB = (it & 1) ? lB1 : lB0;
        ushort_t* nA = (it & 1) ? lA0 : lA1;
        ushort_t* nB = (it & 1) ? lB0 : lB1;
        if (it < 15) {
            int kk = (it + 1) * 128;
            const ushort_t* aSrc = (kk < 1024) ? (hbase + kk) : (xbase + (kk - 1024));
            #pragma unroll
            for (int i = 0; i < 2; ++i) {
                int rlow = (wv * 8 + i * 4 + srow) & 15;
                gload16(aSrc + (size_t)i * 4 * 1024 + (sseg ^ rlow) * 8,
                        nA + (wv * 8 + i * 4) * 128);
            }
            #pragma unroll
            for (int i = 0; i < 4; ++i) {
                int rlow = i * 4 + srow;
                gload16(gB0 + (size_t)i * 4 * 2048 + kk + (sseg ^ rlow) * 8,
                        nB + (wv * 16 + i * 4) * 128);
            }
            asm volatile("s_waitcnt vmcnt(6)" ::: "memory");
        } else {
            asm volatile("s_waitcnt vmcnt(0)" ::: "memory");
        }
        __builtin_amdgcn_s_barrier();
        short8 af[2], bq[4];
        #pragma unroll
        for (int i = 0; i < 2; ++i)
            af[i] = *(const short8*)(cA + (i * 16 + lm) * 128 + ((segk ^ lm) * 8));
        #pragma unroll
        for (int j = 0; j < 4; ++j)
            bq[j] = *(const short8*)(cB + (j * 16 + lm) * 128 + ((segk ^ lm) * 8));
        #pragma unroll
        for (int i = 0; i < 2; ++i)
            #pragma unroll
            for (int j = 0; j < 4; ++j)
                acc[i][j] = __builtin_amdgcn_mfma_f32_16x16x32_bf16(af[i], bq[j], acc[i][j], 0, 0, 0);
        asm volatile("s_waitcnt lgkmcnt(0)" ::: "memory");
        __builtin_amdgcn_s_barrier();
    }

    // ---- wave-private partial store ----
    float* my = lP + wv * (32 * 68);
    #pragma unroll
    for (int i = 0; i < 2; ++i)
        #pragma unroll
        for (int j = 0; j < 4; ++j)
            #pragma unroll
            for (int q = 0; q < 4; ++q)
                my[(i * 16 + quad * 4 + q) * 68 + j * 16 + lm] = acc[i][j][q];
    __syncthreads();

    // ---- LSTM pointwise: 4 wave-partials + bias + sum_l w[l]*P[n][j][l] ----
    float hsave[2];
    #pragma unroll
    for (int e = 0; e < 2; ++e) {
        int idx = tid + e * 256;           // (nl, hl)
        int nl = idx >> 4, hl = idx & 15;
        int base = nl * 68 + hl;
        float s0 = lP[base]      + lP[2176 + base]      + lP[4352 + base]      + lP[6528 + base];
        float s1 = lP[base + 16] + lP[2176 + base + 16] + lP[4352 + base + 16] + lP[6528 + base + 16];
        float s2 = lP[base + 32] + lP[2176 + base + 32] + lP[4352 + base + 32] + lP[6528 + base + 32];
        float s3 = lP[base + 48] + lP[2176 + base + 48] + lP[4352 + base + 48] + lP[6528 + base + 48];
        float wreg[16];
        #pragma unroll
        for (int k = 0; k < 4; ++k)
            *(float4*)(wreg + k * 4) = *(const float4*)(lw + nl * 16 + k * 4);
        int hg = hh0 + hl;
        const ushort_t* pb = g_P + ((size_t)(n0 + nl) * 4096 + hg) * 16;
        float at[4];
        #pragma unroll
        for (int g = 0; g < 4; ++g) {
            const ushort_t* pg = pb + (size_t)g * 1024 * 16;
            float pv[16];
            unp8(*(const uint4*)pg, pv);
            unp8(*(const uint4*)(pg + 8), pv + 8);
            float a = 0.f;
            #pragma unroll
            for (int l = 0; l < 16; ++l) a += wreg[l] * pv[l];
            at[g] = a;
        }
        float ai  = s0 + bias[hg]        + at[0];
        float afv = s1 + bias[1024 + hg] + at[1];
        float ao  = s2 + bias[2048 + hg] + at[2];
        float ag  = s3 + bias[3072 + hg] + at[3];
        float iv = 1.f / (1.f + __expf(-ai));
        float fv = 1.f / (1.f + __expf(-afv));
        float ov = 1.f / (1.f + __expf(-ao));
        float gv = fast_tanh(ag);
        int ng = n0 + nl;
        float cold = g_c[ng * 1024 + hg];
        float cnew = fv * cold + iv * gv;
        float hnew = ov * fast_tanh(cnew);
        g_c[ng * 1024 + hg] = cnew;
        Hout[ng * 1024 + hg] = f2bf(hnew);
        out[(size_t)ng * (T_SEQ * 1024) + (size_t)t * 1024 + hg] = hnew;
        hsave[e] = hnew;
    }

    // ---- logit partial for step t+1 (atomicAdd into rotated buffer) ----
    if (t < T_SEQ - 1) {
        __syncthreads();               // lP reads done before lq overwrite
        #pragma unroll
        for (int e = 0; e < 2; ++e) {
            int idx = tid + e * 256;
            int nl = idx >> 4, hl = idx & 15;
            const ushort_t* ar = g_Ab + (size_t)(n0 + nl) * 16384 + (size_t)(hh0 + hl) * 16;
            float av[16];
            unp8(*(const uint4*)ar, av);
            unp8(*(const uint4*)(ar + 8), av + 8);
            float hv = hsave[e];
            #pragma unroll
            for (int l = 0; l < 16; ++l)
                lq[(nl * 16 + l) * 17 + hl] = hv * av[l];
        }
        __syncthreads();
        #pragma unroll
        for (int e = 0; e < 2; ++e) {
            int idx = tid + e * 256;
            int nl = idx >> 4, l = idx & 15;
            float s = 0.f;
            #pragma unroll
            for (int k = 0; k < 16; ++k) s += lq[(nl * 16 + l) * 17 + k];
            atomicAdd(&g_lg[(t + 1) % 3][n0 + nl][l], s);
        }
    }
}

// ---------------------------------------------------------------------------
extern "C" void kernel_launch(void* const* d_in, const int* in_sizes, int n_in,
                              void* d_out, int out_size, void* d_ws, size_t ws_size,
                              hipStream_t stream) {
    const float* x     = (const float*)d_in[0];
    const float* A     = (const float*)d_in[1];
    const float* Wx    = (const float*)d_in[2];
    const float* Wh    = (const float*)d_in[3];
    const float* Wattn = (const float*)d_in[4];
    const float* bias  = (const float*)d_in[5];
    float* out = (float*)d_out;

    cvt_x<<<8192, 128, 0, stream>>>(x);
    cvt_a<<<256, 256, 0, stream>>>(A);
    prepack_w2<<<dim3(32, 64), 256, 0, stream>>>(Wh, Wx);
    prepack_wat<<<dim3(16, 64), 256, 0, stream>>>(Wattn);
    zero_lg<<<48, 256, 0, stream>>>();
    init_hc<<<1024, 256, 0, stream>>>(A);
    pw_gemm<<<1024, 256, 0, stream>>>();
    for (int t = 0; t < T_SEQ; ++t)
        step_gemm<<<512, 256, 0, stream>>>(out, bias, t);
}